// Round 6
// baseline (168.665 us; speedup 1.0000x reference)
//
#include <hip/hip_runtime.h>

#define T_SEQ 2048
#define C_DIM 1024
#define H_DIM 64
#define B_DIM 8
#define NROW (B_DIM * T_SEQ)  // 16384

typedef __attribute__((ext_vector_type(8))) short short8;
typedef __attribute__((ext_vector_type(4))) float f32x4;

__device__ __forceinline__ short f2bf(float f) {
  unsigned u = __builtin_bit_cast(unsigned, f);
  u += 0x7fffu + ((u >> 16) & 1u);  // round-to-nearest-even
  return (short)(u >> 16);
}

// async global->LDS, 16B per lane.  LDS dest = wave-uniform base + lane*16.
__device__ __forceinline__ void gll16(const void* g, void* l) {
  __builtin_amdgcn_global_load_lds(
      (const __attribute__((address_space(1))) unsigned int*)g,
      (__attribute__((address_space(3))) unsigned int*)l, 16, 0, 0);
}

// ---------------------------------------------------------------------------
// P: Wt[mat][h][k] (bf16) <- W[mat][k][h] (fp32).  LDS tile transpose.
// ---------------------------------------------------------------------------
__global__ __launch_bounds__(256) void w_transpose(
    const float* __restrict__ Wq, const float* __restrict__ Wk,
    const float* __restrict__ Wv, short* __restrict__ Wt) {
  __shared__ float tile[64][65];
  const int mat = blockIdx.x >> 4;
  const int k0 = (blockIdx.x & 15) * 64;
  const float* W = (mat == 0) ? Wq : (mat == 1 ? Wk : Wv);
  const int t = threadIdx.x;
#pragma unroll
  for (int i = 0; i < 16; ++i) {
    int idx = t + i * 256;
    int kk = idx >> 6, h = idx & 63;
    tile[kk][h] = W[(size_t)(k0 + kk) * H_DIM + h];
  }
  __syncthreads();
#pragma unroll
  for (int i = 0; i < 16; ++i) {
    int idx = t + i * 256;
    int h = idx >> 6, kk = idx & 63;
    Wt[((size_t)mat * 64 + h) * C_DIM + k0 + kk] = f2bf(tile[kk][h]);
  }
}

// ---------------------------------------------------------------------------
// K1: QKV projection, m97-style K-loop.  512 blocks (BM=32 rows) x 256 thr
// (4 waves); wave w owns cols w*48..w*48+47 (3 n-tiles) x all 32 rows.
// Per chunk (BK=128):
//   barrier -> issue 12x gll16 staging Wt rows into XOR-swizzled LDS
//   (unit u stored at u^(h&7): frag ds_read_b128 is then <=2-way = free)
//   + 16x direct global b128 A loads into regs (32B contiguous per lane;
//   they ride the same vmcnt(0) drain the compiler emits before the second
//   barrier, so they cost no extra stall) -> barrier -> cvt A, 12 ds_read,
//   24 MFMA.  2-3 blocks/CU co-resident hide each other's barrier drains.
// x fetched exactly once (64 MB).
// ---------------------------------------------------------------------------
__global__ __launch_bounds__(256) void qkv_gemm(
    const float* __restrict__ x, const short* __restrict__ Wt,
    short* __restrict__ q, short* __restrict__ k, short* __restrict__ vt) {
  __shared__ __align__(16) short Bs[192 * 128];  // 48 KB, swizzled
  const int tid = threadIdx.x;
  const int w = tid >> 6, lane = tid & 63;
  const int n16 = lane & 15, quad = lane >> 4;
  const int row0 = blockIdx.x * 32;

  f32x4 acc[2][3];
#pragma unroll
  for (int mt = 0; mt < 2; ++mt)
#pragma unroll
    for (int nt = 0; nt < 3; ++nt) acc[mt][nt] = (f32x4){0.f, 0.f, 0.f, 0.f};

  for (int kc = 0; kc < 8; ++kc) {
    const int k0 = kc * 128;
    __syncthreads();  // all waves done reading previous chunk's Bs
    // stage B chunk: 192 rows x 128 shorts = 3072 units of 16B; 12 gll/thread
#pragma unroll
    for (int i = 0; i < 12; ++i) {
      const int du = w * 768 + i * 64;  // wave-uniform dest base unit
      const int d = du + lane;
      const int h = d >> 4, up = d & 15;
      const int ul = up ^ (h & 7);  // logical k-unit stored at this slot
      gll16(Wt + (size_t)h * C_DIM + k0 + ul * 8, (char*)Bs + (size_t)du * 16);
    }
    // A operand: direct global->reg, 32B contiguous per lane
    float4 a[2][4][2];
#pragma unroll
    for (int mt = 0; mt < 2; ++mt)
#pragma unroll
      for (int kh = 0; kh < 4; ++kh) {
        const float* ap = x + (size_t)(row0 + mt * 16 + n16) * C_DIM + k0 +
                          kh * 32 + quad * 8;
        a[mt][kh][0] = *(const float4*)ap;
        a[mt][kh][1] = *(const float4*)(ap + 4);
      }
    __syncthreads();  // vmcnt(0) drain: Bs valid, a[] valid

    short8 af[2][4];
#pragma unroll
    for (int mt = 0; mt < 2; ++mt)
#pragma unroll
      for (int kh = 0; kh < 4; ++kh) {
#pragma unroll
        for (int e = 0; e < 4; ++e) {
          af[mt][kh][e] = f2bf(((const float*)&a[mt][kh][0])[e]);
          af[mt][kh][e + 4] = f2bf(((const float*)&a[mt][kh][1])[e]);
        }
      }
#pragma unroll
    for (int kh = 0; kh < 4; ++kh)
#pragma unroll
      for (int nt = 0; nt < 3; ++nt) {
        const int h = w * 48 + nt * 16 + n16;
        const int up = (kh * 4 + quad) ^ (h & 7);
        const short8 bf = *(const short8*)(Bs + (size_t)h * 128 + up * 8);
        acc[0][nt] =
            __builtin_amdgcn_mfma_f32_16x16x32_bf16(af[0][kh], bf, acc[0][nt], 0, 0, 0);
        acc[1][nt] =
            __builtin_amdgcn_mfma_f32_16x16x32_bf16(af[1][kh], bf, acc[1][nt], 0, 0, 0);
      }
  }

  const int b = row0 >> 11;
#pragma unroll
  for (int mt = 0; mt < 2; ++mt)
#pragma unroll
    for (int nt = 0; nt < 3; ++nt) {
      const int c = w * 48 + nt * 16 + n16;
      const int mat = c >> 6, cl = c & 63;  // mat is wave-uniform
#pragma unroll
      for (int r = 0; r < 4; ++r) {
        const int row = row0 + mt * 16 + quad * 4 + r;
        const float v = acc[mt][nt][r];
        if (mat == 0)
          q[(size_t)row * H_DIM + cl] = f2bf(v * 0.125f);
        else if (mat == 1)
          k[(size_t)row * H_DIM + cl] = f2bf(v);
        else
          vt[((size_t)b * H_DIM + cl) * T_SEQ + (row & (T_SEQ - 1))] = f2bf(v);
      }
    }
}

// ---------------------------------------------------------------------------
// K2: MFMA flash attention (unchanged from R5 — isolate qkv change, and once
// qkv drops below it this becomes the top dispatch so we get its counters).
// ---------------------------------------------------------------------------
__global__ __launch_bounds__(256) void attn_mfma(
    const short* __restrict__ q, const short* __restrict__ k,
    const short* __restrict__ vt, float* __restrict__ out) {
  __shared__ __align__(16) short pbuf[4][1024];
  __shared__ __align__(16) float oshare[3][1024];
  __shared__ __align__(16) float lshare[3][256];
  const int tid = threadIdx.x;
  const int w = tid >> 6;
  const int lane = tid & 63;
  const int n16 = lane & 15, quad = lane >> 4;
  const int b = blockIdx.x & 7;
  const int qt = (T_SEQ / 16 - 1) - (blockIdx.x >> 3);  // heavy blocks first
  const int r0 = qt * 16;

  const short* qb = q + ((size_t)b * T_SEQ + r0) * H_DIM;
  const short* kb = k + (size_t)b * T_SEQ * H_DIM;
  const short* vb = vt + (size_t)b * H_DIM * T_SEQ;

  const short8 aq0 = *(const short8*)(qb + (size_t)n16 * H_DIM + quad * 8);
  const short8 aq1 = *(const short8*)(qb + (size_t)n16 * H_DIM + 32 + quad * 8);

  f32x4 O[4];
#pragma unroll
  for (int i = 0; i < 4; ++i) O[i] = (f32x4){0.f, 0.f, 0.f, 0.f};
  float lsum[4] = {0.f, 0.f, 0.f, 0.f};

  const int nj = (r0 + 16 + 63) >> 6;  // j-tiles of 64
  for (int jt = w; jt < nj; jt += 4) {
    const int j0 = jt * 64;

    short8 bk[4][2];
#pragma unroll
    for (int nt = 0; nt < 4; ++nt) {
      const short* kp = kb + (size_t)(j0 + nt * 16 + n16) * H_DIM + quad * 8;
      bk[nt][0] = *(const short8*)kp;
      bk[nt][1] = *(const short8*)(kp + 32);
    }

    f32x4 s[4];
#pragma unroll
    for (int nt = 0; nt < 4; ++nt) {
      f32x4 z = (f32x4){0.f, 0.f, 0.f, 0.f};
      z = __builtin_amdgcn_mfma_f32_16x16x32_bf16(aq0, bk[nt][0], z, 0, 0, 0);
      z = __builtin_amdgcn_mfma_f32_16x16x32_bf16(aq1, bk[nt][1], z, 0, 0, 0);
      s[nt] = z;
    }

    const bool full = (j0 + 64 <= r0);  // wave-uniform
#pragma unroll
    for (int nt = 0; nt < 4; ++nt) {
      const int base =
          (nt >> 1) * 512 + ((((nt & 1) << 1) | (n16 >> 3)) * 128) + (n16 & 7);
#pragma unroll
      for (int r = 0; r < 4; ++r) {
        float p;
        if (full) {
          p = __expf(s[nt][r]);
        } else {
          const int j = j0 + nt * 16 + n16;
          const int row = r0 + quad * 4 + r;
          p = (j <= row) ? __expf(s[nt][r]) : 0.f;
        }
        lsum[r] += p;
        pbuf[w][base + (quad * 4 + r) * 8] = f2bf(p);
      }
    }

    short8 bv[4][2];
#pragma unroll
    for (int ht = 0; ht < 4; ++ht)
#pragma unroll
      for (int kh = 0; kh < 2; ++kh)
        bv[ht][kh] = *(const short8*)(vb + (size_t)(ht * 16 + n16) * T_SEQ +
                                      j0 + kh * 32 + quad * 8);

    const short8 ap0 = *(const short8*)(&pbuf[w][0] + lane * 8);
    const short8 ap1 = *(const short8*)(&pbuf[w][0] + 512 + lane * 8);

#pragma unroll
    for (int ht = 0; ht < 4; ++ht) {
      O[ht] = __builtin_amdgcn_mfma_f32_16x16x32_bf16(ap0, bv[ht][0], O[ht], 0, 0, 0);
      O[ht] = __builtin_amdgcn_mfma_f32_16x16x32_bf16(ap1, bv[ht][1], O[ht], 0, 0, 0);
    }
  }

  if (w != 0) {
#pragma unroll
    for (int ht = 0; ht < 4; ++ht)
#pragma unroll
      for (int r = 0; r < 4; ++r)
        oshare[w - 1][(ht * 4 + r) * 64 + lane] = O[ht][r];
#pragma unroll
    for (int r = 0; r < 4; ++r) lshare[w - 1][r * 64 + lane] = lsum[r];
  }
  __syncthreads();
  if (w == 0) {
#pragma unroll
    for (int ht = 0; ht < 4; ++ht)
#pragma unroll
      for (int r = 0; r < 4; ++r) {
        float a = O[ht][r];
#pragma unroll
        for (int ow = 0; ow < 3; ++ow) a += oshare[ow][(ht * 4 + r) * 64 + lane];
        O[ht][r] = a;
      }
#pragma unroll
    for (int r = 0; r < 4; ++r) {
      float vsum = lsum[r];
#pragma unroll
      for (int ow = 0; ow < 3; ++ow) vsum += lshare[ow][r * 64 + lane];
      vsum += __shfl_xor(vsum, 1);
      vsum += __shfl_xor(vsum, 2);
      vsum += __shfl_xor(vsum, 4);
      vsum += __shfl_xor(vsum, 8);
      lsum[r] = vsum;
    }
#pragma unroll
    for (int ht = 0; ht < 4; ++ht)
#pragma unroll
      for (int r = 0; r < 4; ++r)
        out[((size_t)b * T_SEQ + r0 + quad * 4 + r) * H_DIM + ht * 16 + n16] =
            O[ht][r] / lsum[r];
  }
}

extern "C" void kernel_launch(void* const* d_in, const int* in_sizes, int n_in,
                              void* d_out, int out_size, void* d_ws,
                              size_t ws_size, hipStream_t stream) {
  const float* x = (const float*)d_in[0];
  const float* Wq = (const float*)d_in[1];
  const float* Wk = (const float*)d_in[2];
  const float* Wv = (const float*)d_in[3];

  char* ws = (char*)d_ws;
  short* Wt = (short*)ws;                       // 384 KB
  short* q = (short*)(ws + 3 * 64 * 1024 * 2);  // 2 MB each
  short* kk = (short*)(ws + 3 * 64 * 1024 * 2 + 2097152);
  short* vt = (short*)(ws + 3 * 64 * 1024 * 2 + 2 * 2097152);

  w_transpose<<<48, 256, 0, stream>>>(Wq, Wk, Wv, Wt);
  qkv_gemm<<<NROW / 32, 256, 0, stream>>>(x, Wt, q, kk, vt);
  attn_mfma<<<B_DIM * (T_SEQ / 16), 256, 0, stream>>>(q, kk, vt, (float*)d_out);
}

// Round 7
// 143.335 us; speedup vs baseline: 1.1767x; 1.1767x over previous
//
#include <hip/hip_runtime.h>

#define T_SEQ 2048
#define C_DIM 1024
#define H_DIM 64
#define B_DIM 8
#define NROW (B_DIM * T_SEQ)  // 16384

typedef __attribute__((ext_vector_type(8))) short short8;
typedef __attribute__((ext_vector_type(4))) float f32x4;

__device__ __forceinline__ short f2bf(float f) {
  unsigned u = __builtin_bit_cast(unsigned, f);
  u += 0x7fffu + ((u >> 16) & 1u);  // round-to-nearest-even
  return (short)(u >> 16);
}

// ---------------------------------------------------------------------------
// P: Wt[mat][h][k] (bf16) <- W[mat][k][h] (fp32).  LDS tile transpose.
// ---------------------------------------------------------------------------
__global__ __launch_bounds__(256) void w_transpose(
    const float* __restrict__ Wq, const float* __restrict__ Wk,
    const float* __restrict__ Wv, short* __restrict__ Wt) {
  __shared__ float tile[64][65];
  const int mat = blockIdx.x >> 4;
  const int k0 = (blockIdx.x & 15) * 64;
  const float* W = (mat == 0) ? Wq : (mat == 1 ? Wk : Wv);
  const int t = threadIdx.x;
#pragma unroll
  for (int i = 0; i < 16; ++i) {
    int idx = t + i * 256;
    int kk = idx >> 6, h = idx & 63;
    tile[kk][h] = W[(size_t)(k0 + kk) * H_DIM + h];
  }
  __syncthreads();
#pragma unroll
  for (int i = 0; i < 16; ++i) {
    int idx = t + i * 256;
    int h = idx >> 6, kk = idx & 63;
    Wt[((size_t)mat * 64 + h) * C_DIM + k0 + kk] = f2bf(tile[kk][h]);
  }
}

// LDS address (in shorts) for frag unit (tile, kh, quad, n16); the low 16B-unit
// index is XOR-swizzled so both staging writes and frag reads hit the inherent
// 8-phase minimum (no bank conflicts beyond the 1024B/128B floor).
__device__ __forceinline__ int lds_addr(int tile, int kh, int qd, int nn) {
  return tile * 2048 + kh * 512 + (qd * 16 + (nn ^ ((kh * 4 + qd) & 7))) * 8;
}

// ---------------------------------------------------------------------------
// K1: QKV projection.  512 blocks (BM=32 rows) x 256 thr (4 waves), BN=192
// (all three mats -> x is fetched exactly once), BK=128 -> 8 iterations.
// Pipeline per iter: barrier (drains prefetch) -> reg->LDS stores -> barrier
// -> ISSUE next chunk's 16 loads -> 24 MFMAs (their latency overlaps the
// MFMA section instead of a bare barrier).  2 blocks/CU (56 KB LDS) provide
// cross-block overlap of the residual drain.
// ---------------------------------------------------------------------------
__global__ __launch_bounds__(256) void qkv_gemm(
    const float* __restrict__ x, const short* __restrict__ Wt,
    short* __restrict__ q, short* __restrict__ k, short* __restrict__ vt) {
  __shared__ __align__(16) short As[4096];   // 8 KB  (32 x 128)
  __shared__ __align__(16) short Bs[24576];  // 48 KB (192 x 128)
  const int tid = threadIdx.x;
  const int w = tid >> 6, lane = tid & 63;
  const int n16 = lane & 15, quad = lane >> 4;
  const int row0 = blockIdx.x * 32;

  f32x4 acc[2][3];
#pragma unroll
  for (int mt = 0; mt < 2; ++mt)
#pragma unroll
    for (int ln = 0; ln < 3; ++ln) acc[mt][ln] = (f32x4){0.f, 0.f, 0.f, 0.f};

  short8 bstg[12];
  float4 astg[2][2];

  // prefetch chunk 0
#pragma unroll
  for (int i = 0; i < 12; ++i) {
    const int u = i * 256 + tid, h = u >> 4, uk = u & 15;
    bstg[i] = *(const short8*)(Wt + (size_t)h * C_DIM + uk * 8);
  }
#pragma unroll
  for (int i = 0; i < 2; ++i) {
    const int u2 = i * 256 + tid, sr = u2 >> 4, f = u2 & 15;
    const float* ap = x + (size_t)(row0 + sr) * C_DIM + f * 8;
    astg[i][0] = *(const float4*)ap;
    astg[i][1] = *(const float4*)(ap + 4);
  }

  for (int kc = 0; kc < 8; ++kc) {
    __syncthreads();  // drains prefetch; prev chunk's frag readers done
    // reg -> LDS
#pragma unroll
    for (int i = 0; i < 12; ++i) {
      const int u = i * 256 + tid, h = u >> 4, uk = u & 15;
      *(short8*)(Bs + lds_addr(h >> 4, uk >> 2, uk & 3, h & 15)) = bstg[i];
    }
#pragma unroll
    for (int i = 0; i < 2; ++i) {
      const int u2 = i * 256 + tid, sr = u2 >> 4, f = u2 & 15;
      short8 av;
#pragma unroll
      for (int e = 0; e < 4; ++e) {
        av[e] = f2bf(((const float*)&astg[i][0])[e]);
        av[e + 4] = f2bf(((const float*)&astg[i][1])[e]);
      }
      *(short8*)(As + lds_addr(sr >> 4, f >> 2, f & 3, sr & 15)) = av;
    }
    __syncthreads();  // staging visible
    // issue next chunk's loads NOW: latency overlaps the MFMA section below
    if (kc < 7) {
      const int k0n = (kc + 1) * 128;
#pragma unroll
      for (int i = 0; i < 12; ++i) {
        const int u = i * 256 + tid, h = u >> 4, uk = u & 15;
        bstg[i] = *(const short8*)(Wt + (size_t)h * C_DIM + k0n + uk * 8);
      }
#pragma unroll
      for (int i = 0; i < 2; ++i) {
        const int u2 = i * 256 + tid, sr = u2 >> 4, f = u2 & 15;
        const float* ap = x + (size_t)(row0 + sr) * C_DIM + k0n + f * 8;
        astg[i][0] = *(const float4*)ap;
        astg[i][1] = *(const float4*)(ap + 4);
      }
    }
    // compute current chunk
#pragma unroll
    for (int kh = 0; kh < 4; ++kh) {
      short8 afr[2];
#pragma unroll
      for (int mt = 0; mt < 2; ++mt)
        afr[mt] = *(const short8*)(As + lds_addr(mt, kh, quad, n16));
#pragma unroll
      for (int ln = 0; ln < 3; ++ln) {
        const short8 bfr =
            *(const short8*)(Bs + lds_addr(w * 3 + ln, kh, quad, n16));
        acc[0][ln] =
            __builtin_amdgcn_mfma_f32_16x16x32_bf16(afr[0], bfr, acc[0][ln], 0, 0, 0);
        acc[1][ln] =
            __builtin_amdgcn_mfma_f32_16x16x32_bf16(afr[1], bfr, acc[1][ln], 0, 0, 0);
      }
    }
  }

  const int b = row0 >> 11;
#pragma unroll
  for (int mt = 0; mt < 2; ++mt)
#pragma unroll
    for (int ln = 0; ln < 3; ++ln) {
      const int ntg = w * 3 + ln;
      const int mat = ntg >> 2;                  // wave-uniform per frag
      const int cl = (ntg & 3) * 16 + n16;       // column within matrix
#pragma unroll
      for (int r = 0; r < 4; ++r) {
        const int row = row0 + mt * 16 + quad * 4 + r;
        const float v = acc[mt][ln][r];
        if (mat == 0)
          q[(size_t)row * H_DIM + cl] = f2bf(v * 0.125f);
        else if (mat == 1)
          k[(size_t)row * H_DIM + cl] = f2bf(v);
        else
          vt[((size_t)b * H_DIM + cl) * T_SEQ + (row & (T_SEQ - 1))] = f2bf(v);
      }
    }
}

// ---------------------------------------------------------------------------
// K2: MFMA flash attention (byte-identical to R5/R6 — once qkv drops below
// it, this surfaces in top-5 and we finally see its counters).
// ---------------------------------------------------------------------------
__global__ __launch_bounds__(256) void attn_mfma(
    const short* __restrict__ q, const short* __restrict__ k,
    const short* __restrict__ vt, float* __restrict__ out) {
  __shared__ __align__(16) short pbuf[4][1024];
  __shared__ __align__(16) float oshare[3][1024];
  __shared__ __align__(16) float lshare[3][256];
  const int tid = threadIdx.x;
  const int w = tid >> 6;
  const int lane = tid & 63;
  const int n16 = lane & 15, quad = lane >> 4;
  const int b = blockIdx.x & 7;
  const int qt = (T_SEQ / 16 - 1) - (blockIdx.x >> 3);  // heavy blocks first
  const int r0 = qt * 16;

  const short* qb = q + ((size_t)b * T_SEQ + r0) * H_DIM;
  const short* kb = k + (size_t)b * T_SEQ * H_DIM;
  const short* vb = vt + (size_t)b * H_DIM * T_SEQ;

  const short8 aq0 = *(const short8*)(qb + (size_t)n16 * H_DIM + quad * 8);
  const short8 aq1 = *(const short8*)(qb + (size_t)n16 * H_DIM + 32 + quad * 8);

  f32x4 O[4];
#pragma unroll
  for (int i = 0; i < 4; ++i) O[i] = (f32x4){0.f, 0.f, 0.f, 0.f};
  float lsum[4] = {0.f, 0.f, 0.f, 0.f};

  const int nj = (r0 + 16 + 63) >> 6;  // j-tiles of 64
  for (int jt = w; jt < nj; jt += 4) {
    const int j0 = jt * 64;

    short8 bk[4][2];
#pragma unroll
    for (int nt = 0; nt < 4; ++nt) {
      const short* kp = kb + (size_t)(j0 + nt * 16 + n16) * H_DIM + quad * 8;
      bk[nt][0] = *(const short8*)kp;
      bk[nt][1] = *(const short8*)(kp + 32);
    }

    f32x4 s[4];
#pragma unroll
    for (int nt = 0; nt < 4; ++nt) {
      f32x4 z = (f32x4){0.f, 0.f, 0.f, 0.f};
      z = __builtin_amdgcn_mfma_f32_16x16x32_bf16(aq0, bk[nt][0], z, 0, 0, 0);
      z = __builtin_amdgcn_mfma_f32_16x16x32_bf16(aq1, bk[nt][1], z, 0, 0, 0);
      s[nt] = z;
    }

    const bool full = (j0 + 64 <= r0);  // wave-uniform
#pragma unroll
    for (int nt = 0; nt < 4; ++nt) {
      const int base =
          (nt >> 1) * 512 + ((((nt & 1) << 1) | (n16 >> 3)) * 128) + (n16 & 7);
#pragma unroll
      for (int r = 0; r < 4; ++r) {
        float p;
        if (full) {
          p = __expf(s[nt][r]);
        } else {
          const int j = j0 + nt * 16 + n16;
          const int row = r0 + quad * 4 + r;
          p = (j <= row) ? __expf(s[nt][r]) : 0.f;
        }
        lsum[r] += p;
        pbuf[w][base + (quad * 4 + r) * 8] = f2bf(p);
      }
    }

    short8 bv[4][2];
#pragma unroll
    for (int ht = 0; ht < 4; ++ht)
#pragma unroll
      for (int kh = 0; kh < 2; ++kh)
        bv[ht][kh] = *(const short8*)(vb + (size_t)(ht * 16 + n16) * T_SEQ +
                                      j0 + kh * 32 + quad * 8);

    const short8 ap0 = *(const short8*)(&pbuf[w][0] + lane * 8);
    const short8 ap1 = *(const short8*)(&pbuf[w][0] + 512 + lane * 8);

#pragma unroll
    for (int ht = 0; ht < 4; ++ht) {
      O[ht] = __builtin_amdgcn_mfma_f32_16x16x32_bf16(ap0, bv[ht][0], O[ht], 0, 0, 0);
      O[ht] = __builtin_amdgcn_mfma_f32_16x16x32_bf16(ap1, bv[ht][1], O[ht], 0, 0, 0);
    }
  }

  if (w != 0) {
#pragma unroll
    for (int ht = 0; ht < 4; ++ht)
#pragma unroll
      for (int r = 0; r < 4; ++r)
        oshare[w - 1][(ht * 4 + r) * 64 + lane] = O[ht][r];
#pragma unroll
    for (int r = 0; r < 4; ++r) lshare[w - 1][r * 64 + lane] = lsum[r];
  }
  __syncthreads();
  if (w == 0) {
#pragma unroll
    for (int ht = 0; ht < 4; ++ht)
#pragma unroll
      for (int r = 0; r < 4; ++r) {
        float a = O[ht][r];
#pragma unroll
        for (int ow = 0; ow < 3; ++ow) a += oshare[ow][(ht * 4 + r) * 64 + lane];
        O[ht][r] = a;
      }
#pragma unroll
    for (int r = 0; r < 4; ++r) {
      float vsum = lsum[r];
#pragma unroll
      for (int ow = 0; ow < 3; ++ow) vsum += lshare[ow][r * 64 + lane];
      vsum += __shfl_xor(vsum, 1);
      vsum += __shfl_xor(vsum, 2);
      vsum += __shfl_xor(vsum, 4);
      vsum += __shfl_xor(vsum, 8);
      lsum[r] = vsum;
    }
#pragma unroll
    for (int ht = 0; ht < 4; ++ht)
#pragma unroll
      for (int r = 0; r < 4; ++r)
        out[((size_t)b * T_SEQ + r0 + quad * 4 + r) * H_DIM + ht * 16 + n16] =
            O[ht][r] / lsum[r];
  }
}

extern "C" void kernel_launch(void* const* d_in, const int* in_sizes, int n_in,
                              void* d_out, int out_size, void* d_ws,
                              size_t ws_size, hipStream_t stream) {
  const float* x = (const float*)d_in[0];
  const float* Wq = (const float*)d_in[1];
  const float* Wk = (const float*)d_in[2];
  const float* Wv = (const float*)d_in[3];

  char* ws = (char*)d_ws;
  short* Wt = (short*)ws;                       // 384 KB
  short* q = (short*)(ws + 3 * 64 * 1024 * 2);  // 2 MB each
  short* kk = (short*)(ws + 3 * 64 * 1024 * 2 + 2097152);
  short* vt = (short*)(ws + 3 * 64 * 1024 * 2 + 2 * 2097152);

  w_transpose<<<48, 256, 0, stream>>>(Wq, Wk, Wv, Wt);
  qkv_gemm<<<NROW / 32, 256, 0, stream>>>(x, Wt, q, kk, vt);
  attn_mfma<<<B_DIM * (T_SEQ / 16), 256, 0, stream>>>(q, kk, vt, (float*)d_out);
}